// Round 9
// baseline (330.981 us; speedup 1.0000x reference)
//
#include <hip/hip_runtime.h>
#include <hip/hip_bf16.h>
#include <math.h>

constexpr int DXc = 1024;
constexpr int DZc = 1024;
constexpr int LXc = 4096;
constexpr int LZc = 4096;
constexpr int DAc = 1024;   // DATTN
constexpr int DOc = 1024;   // DOUT

typedef __attribute__((ext_vector_type(8))) short bf16x8;   // 8 bf16 = 4 VGPRs
typedef __attribute__((ext_vector_type(4))) float f32x4;
typedef __attribute__((ext_vector_type(8))) _Float16 f16x8;

__device__ __forceinline__ ushort f2bf(float f) {
    __hip_bfloat16 h = __float2bfloat16(f);
    return *reinterpret_cast<ushort*>(&h);
}
__device__ __forceinline__ float bflo(unsigned u) {
    return __builtin_bit_cast(float, u << 16);
}
__device__ __forceinline__ float bfhi(unsigned u) {
    return __builtin_bit_cast(float, u & 0xffff0000u);
}

enum BiasMode { BIAS_NONE, BIAS_M, BIAS_N };

#define SCHED0() __builtin_amdgcn_sched_barrier(0)
// Raw barrier, pinned on both sides so the compiler cannot move ds_reads /
// global_load_lds across it. NO waitcnt drain here — that is the whole point
// of the counted-vmcnt pipeline (T4).
#define BAR2()   do { SCHED0(); __builtin_amdgcn_s_barrier(); SCHED0(); } while (0)
#define LGKM0()  do { asm volatile("s_waitcnt lgkmcnt(0)" ::: "memory"); SCHED0(); } while (0)
#define VMCNT(n) do { asm volatile("s_waitcnt vmcnt(" #n ")" ::: "memory"); SCHED0(); } while (0)

// ---------------------------------------------------------------------------
// 256x256 tile, BK=64, 8 waves (2M x 4N), 8-phase counted-vmcnt schedule
// (T2 swizzle + T3/T4 + T5).  C[m,n] = sum_k A[m,k]*B[n,k], A,B K-major bf16.
// Main loop FROZEN (round-1 verified). SPLIT epilogue stores fp16 partials
// (r8-verified: halves P traffic, absmax unchanged).
// ---------------------------------------------------------------------------
template<BiasMode BMODE, bool OUT_BF16, bool SPLIT>
__device__ __forceinline__ void gemm256(
    const ushort* __restrict__ A, const ushort* __restrict__ B,
    const float* __restrict__ bias, void* __restrict__ Cv,
    int M, int N, int K, int lda, int ldb, int ldc,
    int m0, int n0, int kbase, int zsplit, char* smem)
{
    const int tid  = threadIdx.x;
    const int wid  = tid >> 6, lane = tid & 63;
    const int wr   = wid >> 2, wc = wid & 3;          // 2M x 4N waves
    const int lrow = lane & 15, quad = lane >> 4;
    const int swz  = (lrow & 7) << 4;
    const int cx0  = (quad * 16) ^ swz;               // byte col, kstep 0
    const int cx1  = (64 + quad * 16) ^ swz;          // byte col, kstep 1
    const int raB  = (wr * 16 + lrow) * 128;          // A per-lane row base (bytes)
    const int rbB  = (wc * 16 + lrow) * 128;          // B per-lane row base (bytes)

    char* const Ab0 = smem;                 // A buf0: 32 KB ([256][64] bf16)
    char* const Ab1 = smem + 32768;         // A buf1
    char* const Bb0 = smem + 65536;         // B buf0
    char* const Bb1 = smem + 98304;         // B buf1

    // Stage one half-tile (128 rows x 64 cols) = 2 x global_load_lds(16B).
    // LDS dest linear (wave-uniform base + lane*16); global source inverse-swizzled.
    auto stage = [&](const ushort* __restrict__ Mat, int ld, int r0, int kc,
                     char* dstBuf, int h) {
        #pragma unroll
        for (int r = 0; r < 2; ++r) {
            const int q = h * 16384 + r * 8192 + wid * 1024 + lane * 16; // phys LDS byte
            const int p = q ^ (((q >> 7) & 7) << 4);                    // logical byte
            const ushort* g = Mat + (size_t)(r0 + (p >> 7)) * ld + kc + ((p & 127) >> 1);
            __builtin_amdgcn_global_load_lds(
                (const __attribute__((address_space(1))) void*)g,
                (__attribute__((address_space(3))) void*)(dstBuf + h * 16384 + r * 8192 + wid * 1024),
                16, 0, 0);
        }
    };

    f32x4  acc[8][4] = {};
    bf16x8 alo[4][2], ahi[4][2], blo[2][2], bhi[2][2];

    auto ldLo = [&](char* Abuf, char* Bbuf) {       // 12 ds_read_b128
        #pragma unroll
        for (int m = 0; m < 4; ++m) {
            alo[m][0] = *reinterpret_cast<const bf16x8*>(Abuf + m * 4096 + raB + cx0);
            alo[m][1] = *reinterpret_cast<const bf16x8*>(Abuf + m * 4096 + raB + cx1);
        }
        #pragma unroll
        for (int n = 0; n < 2; ++n) {
            blo[n][0] = *reinterpret_cast<const bf16x8*>(Bbuf + n * 8192 + rbB + cx0);
            blo[n][1] = *reinterpret_cast<const bf16x8*>(Bbuf + n * 8192 + rbB + cx1);
        }
    };
    auto ldAhi = [&](char* Abuf) {                  // 8 ds_read_b128
        #pragma unroll
        for (int m = 0; m < 4; ++m) {
            ahi[m][0] = *reinterpret_cast<const bf16x8*>(Abuf + (m + 4) * 4096 + raB + cx0);
            ahi[m][1] = *reinterpret_cast<const bf16x8*>(Abuf + (m + 4) * 4096 + raB + cx1);
        }
    };
    auto ldBhi = [&](char* Bbuf) {                  // 4 ds_read_b128
        #pragma unroll
        for (int n = 0; n < 2; ++n) {
            bhi[n][0] = *reinterpret_cast<const bf16x8*>(Bbuf + (n + 2) * 8192 + rbB + cx0);
            bhi[n][1] = *reinterpret_cast<const bf16x8*>(Bbuf + (n + 2) * 8192 + rbB + cx1);
        }
    };
    auto mmaQ = [&](bf16x8 (&a)[4][2], bf16x8 (&b)[2][2], int mh, int nh) {  // 16 MFMA
        __builtin_amdgcn_s_setprio(1);
        #pragma unroll
        for (int m = 0; m < 4; ++m)
            #pragma unroll
            for (int n = 0; n < 2; ++n) {
                f32x4& c = acc[mh * 4 + m][nh * 2 + n];
                c = __builtin_amdgcn_mfma_f32_16x16x32_bf16(a[m][0], b[n][0], c, 0, 0, 0);
                c = __builtin_amdgcn_mfma_f32_16x16x32_bf16(a[m][1], b[n][1], c, 0, 0, 0);
            }
        __builtin_amdgcn_s_setprio(0);
    };

    const int NIT = K >> 7;   // iterations; 2 K-tiles (BK=64) each

    // Prologue: tile0 {A0,B0,B1,A1} then tile1 {A0,B0,B1}; A1(tile1) comes in-loop p1.
    stage(A, lda, m0, kbase,      Ab0, 0);
    stage(B, ldb, n0, kbase,      Bb0, 0);
    stage(B, ldb, n0, kbase,      Bb0, 1);
    stage(A, lda, m0, kbase,      Ab0, 1);
    VMCNT(4);
    stage(A, lda, m0, kbase + 64, Ab1, 0);
    stage(B, ldb, n0, kbase + 64, Bb1, 0);
    stage(B, ldb, n0, kbase + 64, Bb1, 1);
    VMCNT(6);                 // ensures all of tile0 resident
    BAR2();

    #pragma unroll 1
    for (int it = 0; it < NIT; ++it) {
        const bool st  = (it < NIT - 1);
        const int kU   = kbase + (2 * it + 1) * 64;
        const int kT2  = kbase + (2 * it + 2) * 64;
        const int kT3  = kbase + (2 * it + 3) * 64;

        // ---- p1: tile T (buf0), quadrant (m-lo, n-lo)
        ldLo(Ab0, Bb0);
        stage(A, lda, m0, kU, Ab1, 1);                    // A1(U) - always needed
        asm volatile("s_waitcnt lgkmcnt(8)" ::: "memory");
        BAR2(); LGKM0();
        mmaQ(alo, blo, 0, 0);
        BAR2();
        // ---- p2: (m-lo, n-hi)
        ldBhi(Bb0);
        if (st) stage(A, lda, m0, kT2, Ab0, 0);           // A0(T+2)
        BAR2(); LGKM0();
        mmaQ(alo, bhi, 0, 1);
        BAR2();
        // ---- p3: (m-hi, n-hi)
        ldAhi(Ab0);
        if (st) stage(B, ldb, n0, kT2, Bb0, 0);           // B0(T+2)
        BAR2(); LGKM0();
        mmaQ(ahi, bhi, 1, 1);
        BAR2();
        // ---- p4: (m-hi, n-lo); once-per-K-tile vmcnt
        if (st) { stage(B, ldb, n0, kT2, Bb0, 1); VMCNT(6); }   // B1(T+2)
        else    { VMCNT(0); }                             // epilogue drain
        BAR2();
        mmaQ(ahi, blo, 1, 0);
        BAR2();
        // ---- p5: tile U (buf1), quadrant (m-lo, n-lo)
        ldLo(Ab1, Bb1);
        if (st) stage(A, lda, m0, kT2, Ab0, 1);           // A1(T+2)
        asm volatile("s_waitcnt lgkmcnt(8)" ::: "memory");
        BAR2(); LGKM0();
        mmaQ(alo, blo, 0, 0);
        BAR2();
        // ---- p6: (m-lo, n-hi)
        ldBhi(Bb1);
        if (st) stage(A, lda, m0, kT3, Ab1, 0);           // A0(T+3)
        BAR2(); LGKM0();
        mmaQ(alo, bhi, 0, 1);
        BAR2();
        // ---- p7: (m-hi, n-hi)
        ldAhi(Ab1);
        if (st) stage(B, ldb, n0, kT3, Bb1, 0);           // B0(T+3)
        BAR2(); LGKM0();
        mmaQ(ahi, bhi, 1, 1);
        BAR2();
        // ---- p8: (m-hi, n-lo)
        if (st) { stage(B, ldb, n0, kT3, Bb1, 1); VMCNT(6); }   // B1(T+3)
        else    { VMCNT(0); }
        BAR2();
        mmaQ(ahi, blo, 1, 0);
        BAR2();
    }

    // Epilogue: row = m0 + 32m + wr*16 + quad*4 + r ; col = n0 + 64n + wc*16 + lrow
    _Float16* Ch = (_Float16*)Cv + (SPLIT ? (size_t)zsplit * (size_t)M * ldc : 0);
    ushort*   Cb = (ushort*)Cv;
    #pragma unroll
    for (int m = 0; m < 8; ++m) {
        const int rowb = m0 + 32 * m + wr * 16 + quad * 4;
        #pragma unroll
        for (int r = 0; r < 4; ++r) {
            const int row = rowb + r;
            const float bm = (BMODE == BIAS_M) ? bias[row] : 0.0f;
            #pragma unroll
            for (int n = 0; n < 4; ++n) {
                const int col = n0 + 64 * n + wc * 16 + lrow;
                float v = acc[m][n][r] + ((BMODE == BIAS_N) ? bias[col] : bm);
                if (OUT_BF16) Cb[(size_t)row * ldc + col] = f2bf(v);
                else          Ch[(size_t)row * ldc + col] = (_Float16)v;
            }
        }
    }
}

// ---------------------------------------------------------------------------
// Batched projection GEMM: one dispatch for q, k, v (192 blocks of 512 thr).
// ---------------------------------------------------------------------------
__global__ __launch_bounds__(512, 2)
void proj256_kernel(const ushort* __restrict__ XT, const ushort* __restrict__ ZT,
                    const ushort* __restrict__ Wqb, const ushort* __restrict__ Wkb,
                    const ushort* __restrict__ Wvb,
                    const float* __restrict__ bq, const float* __restrict__ bk,
                    const float* __restrict__ bv,
                    ushort* __restrict__ qT, ushort* __restrict__ kT,
                    ushort* __restrict__ vB)
{
    extern __shared__ char smem[];
    int b = blockIdx.x;
    if (b < 64) {
        gemm256<BIAS_N, true, false>(XT, Wqb, bq, qT, LXc, DAc, DXc, DXc, DXc, DAc,
                                     (b >> 2) * 256, (b & 3) * 256, 0, 0, smem);
    } else if (b < 128) {
        b -= 64;
        gemm256<BIAS_N, true, false>(ZT, Wkb, bk, kT, LZc, DAc, DZc, DZc, DZc, DAc,
                                     (b >> 2) * 256, (b & 3) * 256, 0, 0, smem);
    } else {
        b -= 128;
        gemm256<BIAS_M, true, false>(Wvb, ZT, bv, vB, DOc, LZc, DZc, DZc, DZc, LZc,
                                     (b >> 4) * 256, (b & 15) * 256, 0, 0, smem);
    }
}

// Score GEMM: sTb[x,z] = sum_d qT[x,d] kT[z,d]  (bf16 out, no mask). 256 blocks.
__global__ __launch_bounds__(512, 2)
void score256_kernel(const ushort* __restrict__ qT, const ushort* __restrict__ kT,
                     ushort* __restrict__ sTb)
{
    extern __shared__ char smem[];
    const int b = blockIdx.x;
    gemm256<BIAS_NONE, true, false>(qT, kT, nullptr, sTb, LXc, LZc, DAc, DAc, DAc, LZc,
                                    (b >> 4) * 256, (b & 15) * 256, 0, 0, smem);
}

// ---------------------------------------------------------------------------
// Fused tail: softmax -> out GEMM (split-K fp16) -> reduce, ONE dispatch.
// grid (16,4,4) = 256 blocks x 512 thr, 1 block/CU => co-resident (r6-proven).
// Counter sync (r6-proven fence pattern), no grid-wide barrier:
//   cnt1[g], g = x-row-group (16 groups x 16 contributors): softmax done
//   cnt2[t], t = (o,x) tile   (64 tiles  x  4 contributors): partials done
// ---------------------------------------------------------------------------
__global__ __launch_bounds__(512, 2)
void outfused_kernel(const ushort* __restrict__ vB, ushort* __restrict__ sTb,
                     const unsigned* __restrict__ bits, _Float16* __restrict__ P,
                     float* __restrict__ out, unsigned* __restrict__ cnt)
{
    extern __shared__ char smem[];
    const int bx = blockIdx.x, by = blockIdx.y, bz = blockIdx.z;
    const int lid = bx + 16 * by + 64 * bz;          // [0,256)
    const int tid = threadIdx.x;
    const int lane = tid & 63, wid = tid >> 6;
    unsigned* cnt1 = cnt;        // 16 words
    unsigned* cnt2 = cnt + 16;   // 64 words

    // ---- phase A: softmax rows [lid*16, lid*16+16), wave-per-row (r2-proven)
    {
        constexpr float scale = 1.0f / 32.0f;   // 1/sqrt(1024)
        constexpr float MASKV = -1000.0f / 32.0f;
        #pragma unroll 1
        for (int i = 0; i < 2; ++i) {
            const int x = lid * 16 + wid * 2 + i;
            ushort* row = sTb + (size_t)x * LZc;
            float v[64];
            float mx = -1e30f;
            #pragma unroll
            for (int r = 0; r < 8; ++r) {
                const uint4 pk = *reinterpret_cast<const uint4*>(row + (size_t)(r * 512 + lane * 8));
                const unsigned* wp = reinterpret_cast<const unsigned*>(&pk);
                const unsigned mb = (bits[(size_t)x * 128 + r * 16 + (lane >> 2)] >> ((lane & 3) * 8)) & 0xffu;
                #pragma unroll
                for (int j = 0; j < 4; ++j) {
                    const float lo = ((mb >> (2 * j))     & 1u) ? bflo(wp[j]) * scale : MASKV;
                    const float hi = ((mb >> (2 * j + 1)) & 1u) ? bfhi(wp[j]) * scale : MASKV;
                    v[r * 8 + 2 * j]     = lo;
                    v[r * 8 + 2 * j + 1] = hi;
                    mx = fmaxf(mx, fmaxf(lo, hi));
                }
            }
            #pragma unroll
            for (int off = 32; off > 0; off >>= 1)
                mx = fmaxf(mx, __shfl_xor(mx, off, 64));
            float sum = 0.0f;
            #pragma unroll
            for (int k = 0; k < 64; ++k) {
                v[k] = __expf(v[k] - mx);
                sum += v[k];
            }
            #pragma unroll
            for (int off = 32; off > 0; off >>= 1)
                sum += __shfl_xor(sum, off, 64);
            const float inv = 1.0f / sum;
            #pragma unroll
            for (int r = 0; r < 8; ++r) {
                uint4 pk;
                unsigned* wp = reinterpret_cast<unsigned*>(&pk);
                #pragma unroll
                for (int j = 0; j < 4; ++j) {
                    const unsigned lo = f2bf(v[r * 8 + 2 * j] * inv);
                    const unsigned hi = f2bf(v[r * 8 + 2 * j + 1] * inv);
                    wp[j] = lo | (hi << 16);
                }
                *reinterpret_cast<uint4*>(row + (size_t)(r * 512 + lane * 8)) = pk;
            }
        }
    }
    // publish softmax of group lid>>4; wait for group bx (the one our GEMM reads)
    __syncthreads();
    if (tid == 0) {
        __builtin_amdgcn_fence(__ATOMIC_RELEASE, "agent");
        __hip_atomic_fetch_add(&cnt1[lid >> 4], 1u, __ATOMIC_RELAXED, __HIP_MEMORY_SCOPE_AGENT);
        while (__hip_atomic_load(&cnt1[bx], __ATOMIC_RELAXED, __HIP_MEMORY_SCOPE_AGENT) < 16u)
            __builtin_amdgcn_s_sleep(2);
    }
    __syncthreads();
    __builtin_amdgcn_fence(__ATOMIC_ACQUIRE, "agent");

    // ---- phase B: out GEMM split-K=4 -> fp16 partials (frozen gemm256)
    gemm256<BIAS_NONE, false, true>(vB, sTb, nullptr, P, DOc, LXc, LZc / 4,
                                    LZc, LZc, LXc,
                                    by * 256, bx * 256, bz * (LZc / 4), bz, smem);

    // publish partials of tile (bx,by); wait for all 4 split-K siblings
    __syncthreads();
    if (tid == 0) {
        __builtin_amdgcn_fence(__ATOMIC_RELEASE, "agent");
        __hip_atomic_fetch_add(&cnt2[bx + 16 * by], 1u, __ATOMIC_RELAXED, __HIP_MEMORY_SCOPE_AGENT);
        while (__hip_atomic_load(&cnt2[bx + 16 * by], __ATOMIC_RELAXED, __HIP_MEMORY_SCOPE_AGENT) < 4u)
            __builtin_amdgcn_s_sleep(2);
    }
    __syncthreads();
    __builtin_amdgcn_fence(__ATOMIC_ACQUIRE, "agent");

    // ---- phase C: reduce quarter-tile: o-rows [by*256+bz*64, +64), x-cols [bx*256, +256)
    {
        constexpr size_t total = (size_t)DOc * LXc;
        const int r  = tid >> 3;             // [0,64)
        const int sg = (tid & 7) * 32;       // 32 cols per thread
        const int o  = by * 256 + bz * 64 + r;
        const int x0 = bx * 256 + sg;
        float s[32] = {};
        #pragma unroll
        for (int p = 0; p < 4; ++p) {
            const _Float16* pp = P + (size_t)p * total + (size_t)o * LXc + x0;
            #pragma unroll
            for (int v8 = 0; v8 < 4; ++v8) {
                const f16x8 t = *reinterpret_cast<const f16x8*>(pp + v8 * 8);
                #pragma unroll
                for (int j = 0; j < 8; ++j) s[v8 * 8 + j] += (float)t[j];
            }
        }
        float* op = out + (size_t)o * LXc + x0;
        #pragma unroll
        for (int q = 0; q < 8; ++q) {
            float4 o4 = {s[q * 4], s[q * 4 + 1], s[q * 4 + 2], s[q * 4 + 3]};
            *reinterpret_cast<float4*>(op + q * 4) = o4;
        }
    }
}

// ---------------------------------------------------------------------------
// Prep (one dispatch, 13313 blocks) — round-1 measured-best, FROZEN:
// X->XT bf16 LDS transpose, Z->ZT, Wq/Wk/Wv fp32->bf16, mask pack (scalar,
// 2048-block spread — r1-proven; r8 showed concentrating it on 64 CUs loses).
// Final block zeroes the 80 sync counters.
// ---------------------------------------------------------------------------
__global__ __launch_bounds__(256)
void prep_kernel(const float* __restrict__ X, const float* __restrict__ Z,
                 const float* __restrict__ Wq, const float* __restrict__ Wk,
                 const float* __restrict__ Wv, const int* __restrict__ mask,
                 ushort* __restrict__ XT, ushort* __restrict__ ZT,
                 ushort* __restrict__ Wqb, ushort* __restrict__ Wkb,
                 ushort* __restrict__ Wvb, unsigned* __restrict__ bits,
                 unsigned* __restrict__ cnt)
{
    __shared__ float tile[32][33];
    const int tid = threadIdx.x;
    int b = blockIdx.x;

    if (b < 8192) {   // two transposes, 4096 blocks each: (R=1024, C=4096)
        const float* in  = (b < 4096) ? X : Z;
        ushort*      out = (b < 4096) ? XT : ZT;
        const int local = b & 4095;
        const int bx = local & 127, by = local >> 7;     // C/32=128 tiles in x
        const int c0 = bx * 32, r0 = by * 32;
        const int tx = tid & 31, ty = tid >> 5;          // 32 x 8
        #pragma unroll
        for (int i = 0; i < 32; i += 8)
            tile[ty + i][tx] = in[(size_t)(r0 + ty + i) * LXc + c0 + tx];
        __syncthreads();
        #pragma unroll
        for (int i = 0; i < 32; i += 8)
            out[(size_t)(c0 + ty + i) * DXc + r0 + tx] = f2bf(tile[tx][ty + i]);
        return;
    }
    if (b < 11264) {  // three weight converts, 1024 blocks each (1M elems)
        b -= 8192;
        const float* in  = (b < 1024) ? Wq : (b < 2048) ? Wk : Wv;
        ushort*      out = (b < 1024) ? Wqb : (b < 2048) ? Wkb : Wvb;
        const int local = b & 1023;
        const size_t i = ((size_t)local * 256 + tid) * 4;
        float4 f = *reinterpret_cast<const float4*>(in + i);
        ushort4 u;
        u.x = f2bf(f.x); u.y = f2bf(f.y); u.z = f2bf(f.z); u.w = f2bf(f.w);
        *reinterpret_cast<ushort4*>(out + i) = u;
        return;
    }
    if (b < 13312) {  // mask pack: 2048 blocks; block = (xb in [0,16), zb in [0,128))
        b -= 11264;
        const int xb = b & 15, zb = b >> 4;
        const int x  = xb * 256 + tid;
        const int z0 = zb * 32;
        unsigned w = 0;
        #pragma unroll 8
        for (int i = 0; i < 32; ++i)
            w |= (mask[(size_t)(z0 + i) * LXc + x] != 0 ? 1u : 0u) << i;
        bits[(size_t)x * (LZc / 32) + zb] = w;
        return;
    }
    // final block: zero the sync counters (16 + 64 words)
    if (tid < 80) cnt[tid] = 0u;
}

// ---------------------------------------------------------------------------
extern "C" void kernel_launch(void* const* d_in, const int* in_sizes, int n_in,
                              void* d_out, int out_size, void* d_ws, size_t ws_size,
                              hipStream_t stream)
{
    const float* X    = (const float*)d_in[0];
    const float* Z    = (const float*)d_in[1];
    const int*   mask = (const int*)  d_in[2];
    const float* Wq   = (const float*)d_in[3];
    const float* bq   = (const float*)d_in[4];
    const float* Wk   = (const float*)d_in[5];
    const float* bk   = (const float*)d_in[6];
    const float* Wv   = (const float*)d_in[7];
    const float* bv   = (const float*)d_in[8];
    float* out = (float*)d_out;

    // 128 KiB dynamic LDS opt-in (once; host-side, not a stream op).
    static bool inited = false;
    if (!inited) {
        (void)hipFuncSetAttribute((const void*)proj256_kernel,
                                  hipFuncAttributeMaxDynamicSharedMemorySize, 131072);
        (void)hipFuncSetAttribute((const void*)score256_kernel,
                                  hipFuncAttributeMaxDynamicSharedMemorySize, 131072);
        (void)hipFuncSetAttribute((const void*)outfused_kernel,
                                  hipFuncAttributeMaxDynamicSharedMemorySize, 131072);
        inited = true;
    }

    // ws layout (106 MB). P (32 MB fp16 at offset 0) OVERLAYS XT/ZT/W/qT and
    // the first 2 MB of kT — all dead by the time outfused writes P.
    char* ws = (char*)d_ws;
    ushort*   XT   = (ushort*)(ws);                   // 8 MB   [dead after proj]
    ushort*   ZT   = (ushort*)(ws + ( 8ull << 20));   // 8 MB   [dead after proj]
    ushort*   Wqb  = (ushort*)(ws + (16ull << 20));   // 2 MB   [dead after proj]
    ushort*   Wkb  = (ushort*)(ws + (18ull << 20));   // 2 MB   [dead after proj]
    ushort*   Wvb  = (ushort*)(ws + (20ull << 20));   // 2 MB   [dead after proj]
    ushort*   qT   = (ushort*)(ws + (22ull << 20));   // 8 MB   [dead after score]
    ushort*   kT   = (ushort*)(ws + (30ull << 20));   // 8 MB   [dead after score]
    _Float16* P    = (_Float16*)(ws);                 // 32 MB  [outfused partials]
    unsigned* cnt  = (unsigned*)(ws + (60ull << 20)); // 320 B  [sync counters]
    ushort*   vB   = (ushort*)(ws + (64ull << 20));   // 8 MB
    ushort*   sTb  = (ushort*)(ws + (72ull << 20));   // 32 MB
    unsigned* bits = (unsigned*)(ws + (104ull << 20));// 2 MB

    prep_kernel<<<dim3(13313), 256, 0, stream>>>(X, Z, Wq, Wk, Wv, mask,
                                                 XT, ZT, Wqb, Wkb, Wvb, bits, cnt);
    proj256_kernel<<<dim3(192), 512, 131072, stream>>>(XT, ZT, Wqb, Wkb, Wvb,
                                                       bq, bk, bv, qT, kT, vB);
    score256_kernel<<<dim3(256), 512, 131072, stream>>>(qT, kT, sTb);
    outfused_kernel<<<dim3(16, 4, 4), 512, 131072, stream>>>(vB, sTb, bits, P, out, cnt);
}

// Round 10
// 274.341 us; speedup vs baseline: 1.2065x; 1.2065x over previous
//
#include <hip/hip_runtime.h>
#include <hip/hip_bf16.h>
#include <math.h>

constexpr int DXc = 1024;
constexpr int DZc = 1024;
constexpr int LXc = 4096;
constexpr int LZc = 4096;
constexpr int DAc = 1024;   // DATTN
constexpr int DOc = 1024;   // DOUT

typedef __attribute__((ext_vector_type(8))) short bf16x8;   // 8 bf16 = 4 VGPRs
typedef __attribute__((ext_vector_type(4))) float f32x4;
typedef __attribute__((ext_vector_type(8))) _Float16 f16x8;

__device__ __forceinline__ ushort f2bf(float f) {
    __hip_bfloat16 h = __float2bfloat16(f);
    return *reinterpret_cast<ushort*>(&h);
}
__device__ __forceinline__ float bflo(unsigned u) {
    return __builtin_bit_cast(float, u << 16);
}
__device__ __forceinline__ float bfhi(unsigned u) {
    return __builtin_bit_cast(float, u & 0xffff0000u);
}

enum BiasMode { BIAS_NONE, BIAS_M, BIAS_N };

#define SCHED0() __builtin_amdgcn_sched_barrier(0)
// Raw barrier, pinned on both sides so the compiler cannot move ds_reads /
// global_load_lds across it. NO waitcnt drain here — that is the whole point
// of the counted-vmcnt pipeline (T4).
#define BAR2()   do { SCHED0(); __builtin_amdgcn_s_barrier(); SCHED0(); } while (0)
#define LGKM0()  do { asm volatile("s_waitcnt lgkmcnt(0)" ::: "memory"); SCHED0(); } while (0)
#define VMCNT(n) do { asm volatile("s_waitcnt vmcnt(" #n ")" ::: "memory"); SCHED0(); } while (0)

// ---------------------------------------------------------------------------
// 256x256 tile, BK=64, 8 waves (2M x 4N), 8-phase counted-vmcnt schedule
// (T2 swizzle + T3/T4 + T5).  C[m,n] = sum_k A[m,k]*B[n,k], A,B K-major bf16.
// Main loop FROZEN (round-1 verified). SPLIT epilogue stores fp16 partials
// (r8-verified: halves P traffic, absmax unchanged).
// ---------------------------------------------------------------------------
template<BiasMode BMODE, bool OUT_BF16, bool SPLIT>
__device__ __forceinline__ void gemm256(
    const ushort* __restrict__ A, const ushort* __restrict__ B,
    const float* __restrict__ bias, void* __restrict__ Cv,
    int M, int N, int K, int lda, int ldb, int ldc,
    int m0, int n0, int kbase, int zsplit, char* smem)
{
    const int tid  = threadIdx.x;
    const int wid  = tid >> 6, lane = tid & 63;
    const int wr   = wid >> 2, wc = wid & 3;          // 2M x 4N waves
    const int lrow = lane & 15, quad = lane >> 4;
    const int swz  = (lrow & 7) << 4;
    const int cx0  = (quad * 16) ^ swz;               // byte col, kstep 0
    const int cx1  = (64 + quad * 16) ^ swz;          // byte col, kstep 1
    const int raB  = (wr * 16 + lrow) * 128;          // A per-lane row base (bytes)
    const int rbB  = (wc * 16 + lrow) * 128;          // B per-lane row base (bytes)

    char* const Ab0 = smem;                 // A buf0: 32 KB ([256][64] bf16)
    char* const Ab1 = smem + 32768;         // A buf1
    char* const Bb0 = smem + 65536;         // B buf0
    char* const Bb1 = smem + 98304;         // B buf1

    // Stage one half-tile (128 rows x 64 cols) = 2 x global_load_lds(16B).
    // LDS dest linear (wave-uniform base + lane*16); global source inverse-swizzled.
    auto stage = [&](const ushort* __restrict__ Mat, int ld, int r0, int kc,
                     char* dstBuf, int h) {
        #pragma unroll
        for (int r = 0; r < 2; ++r) {
            const int q = h * 16384 + r * 8192 + wid * 1024 + lane * 16; // phys LDS byte
            const int p = q ^ (((q >> 7) & 7) << 4);                    // logical byte
            const ushort* g = Mat + (size_t)(r0 + (p >> 7)) * ld + kc + ((p & 127) >> 1);
            __builtin_amdgcn_global_load_lds(
                (const __attribute__((address_space(1))) void*)g,
                (__attribute__((address_space(3))) void*)(dstBuf + h * 16384 + r * 8192 + wid * 1024),
                16, 0, 0);
        }
    };

    f32x4  acc[8][4] = {};
    bf16x8 alo[4][2], ahi[4][2], blo[2][2], bhi[2][2];

    auto ldLo = [&](char* Abuf, char* Bbuf) {       // 12 ds_read_b128
        #pragma unroll
        for (int m = 0; m < 4; ++m) {
            alo[m][0] = *reinterpret_cast<const bf16x8*>(Abuf + m * 4096 + raB + cx0);
            alo[m][1] = *reinterpret_cast<const bf16x8*>(Abuf + m * 4096 + raB + cx1);
        }
        #pragma unroll
        for (int n = 0; n < 2; ++n) {
            blo[n][0] = *reinterpret_cast<const bf16x8*>(Bbuf + n * 8192 + rbB + cx0);
            blo[n][1] = *reinterpret_cast<const bf16x8*>(Bbuf + n * 8192 + rbB + cx1);
        }
    };
    auto ldAhi = [&](char* Abuf) {                  // 8 ds_read_b128
        #pragma unroll
        for (int m = 0; m < 4; ++m) {
            ahi[m][0] = *reinterpret_cast<const bf16x8*>(Abuf + (m + 4) * 4096 + raB + cx0);
            ahi[m][1] = *reinterpret_cast<const bf16x8*>(Abuf + (m + 4) * 4096 + raB + cx1);
        }
    };
    auto ldBhi = [&](char* Bbuf) {                  // 4 ds_read_b128
        #pragma unroll
        for (int n = 0; n < 2; ++n) {
            bhi[n][0] = *reinterpret_cast<const bf16x8*>(Bbuf + (n + 2) * 8192 + rbB + cx0);
            bhi[n][1] = *reinterpret_cast<const bf16x8*>(Bbuf + (n + 2) * 8192 + rbB + cx1);
        }
    };
    auto mmaQ = [&](bf16x8 (&a)[4][2], bf16x8 (&b)[2][2], int mh, int nh) {  // 16 MFMA
        __builtin_amdgcn_s_setprio(1);
        #pragma unroll
        for (int m = 0; m < 4; ++m)
            #pragma unroll
            for (int n = 0; n < 2; ++n) {
                f32x4& c = acc[mh * 4 + m][nh * 2 + n];
                c = __builtin_amdgcn_mfma_f32_16x16x32_bf16(a[m][0], b[n][0], c, 0, 0, 0);
                c = __builtin_amdgcn_mfma_f32_16x16x32_bf16(a[m][1], b[n][1], c, 0, 0, 0);
            }
        __builtin_amdgcn_s_setprio(0);
    };

    const int NIT = K >> 7;   // iterations; 2 K-tiles (BK=64) each

    // Prologue: tile0 {A0,B0,B1,A1} then tile1 {A0,B0,B1}; A1(tile1) comes in-loop p1.
    stage(A, lda, m0, kbase,      Ab0, 0);
    stage(B, ldb, n0, kbase,      Bb0, 0);
    stage(B, ldb, n0, kbase,      Bb0, 1);
    stage(A, lda, m0, kbase,      Ab0, 1);
    VMCNT(4);
    stage(A, lda, m0, kbase + 64, Ab1, 0);
    stage(B, ldb, n0, kbase + 64, Bb1, 0);
    stage(B, ldb, n0, kbase + 64, Bb1, 1);
    VMCNT(6);                 // ensures all of tile0 resident
    BAR2();

    #pragma unroll 1
    for (int it = 0; it < NIT; ++it) {
        const bool st  = (it < NIT - 1);
        const int kU   = kbase + (2 * it + 1) * 64;
        const int kT2  = kbase + (2 * it + 2) * 64;
        const int kT3  = kbase + (2 * it + 3) * 64;

        // ---- p1: tile T (buf0), quadrant (m-lo, n-lo)
        ldLo(Ab0, Bb0);
        stage(A, lda, m0, kU, Ab1, 1);                    // A1(U) - always needed
        asm volatile("s_waitcnt lgkmcnt(8)" ::: "memory");
        BAR2(); LGKM0();
        mmaQ(alo, blo, 0, 0);
        BAR2();
        // ---- p2: (m-lo, n-hi)
        ldBhi(Bb0);
        if (st) stage(A, lda, m0, kT2, Ab0, 0);           // A0(T+2)
        BAR2(); LGKM0();
        mmaQ(alo, bhi, 0, 1);
        BAR2();
        // ---- p3: (m-hi, n-hi)
        ldAhi(Ab0);
        if (st) stage(B, ldb, n0, kT2, Bb0, 0);           // B0(T+2)
        BAR2(); LGKM0();
        mmaQ(ahi, bhi, 1, 1);
        BAR2();
        // ---- p4: (m-hi, n-lo); once-per-K-tile vmcnt
        if (st) { stage(B, ldb, n0, kT2, Bb0, 1); VMCNT(6); }   // B1(T+2)
        else    { VMCNT(0); }                             // epilogue drain
        BAR2();
        mmaQ(ahi, blo, 1, 0);
        BAR2();
        // ---- p5: tile U (buf1), quadrant (m-lo, n-lo)
        ldLo(Ab1, Bb1);
        if (st) stage(A, lda, m0, kT2, Ab0, 1);           // A1(T+2)
        asm volatile("s_waitcnt lgkmcnt(8)" ::: "memory");
        BAR2(); LGKM0();
        mmaQ(alo, blo, 0, 0);
        BAR2();
        // ---- p6: (m-lo, n-hi)
        ldBhi(Bb1);
        if (st) stage(A, lda, m0, kT3, Ab1, 0);           // A0(T+3)
        BAR2(); LGKM0();
        mmaQ(alo, bhi, 0, 1);
        BAR2();
        // ---- p7: (m-hi, n-hi)
        ldAhi(Ab1);
        if (st) stage(B, ldb, n0, kT3, Bb1, 0);           // B0(T+3)
        BAR2(); LGKM0();
        mmaQ(ahi, bhi, 1, 1);
        BAR2();
        // ---- p8: (m-hi, n-lo)
        if (st) { stage(B, ldb, n0, kT3, Bb1, 1); VMCNT(6); }   // B1(T+3)
        else    { VMCNT(0); }
        BAR2();
        mmaQ(ahi, blo, 1, 0);
        BAR2();
    }

    // Epilogue: row = m0 + 32m + wr*16 + quad*4 + r ; col = n0 + 64n + wc*16 + lrow
    _Float16* Ch = (_Float16*)Cv + (SPLIT ? (size_t)zsplit * (size_t)M * ldc : 0);
    ushort*   Cb = (ushort*)Cv;
    #pragma unroll
    for (int m = 0; m < 8; ++m) {
        const int rowb = m0 + 32 * m + wr * 16 + quad * 4;
        #pragma unroll
        for (int r = 0; r < 4; ++r) {
            const int row = rowb + r;
            const float bm = (BMODE == BIAS_M) ? bias[row] : 0.0f;
            #pragma unroll
            for (int n = 0; n < 4; ++n) {
                const int col = n0 + 64 * n + wc * 16 + lrow;
                float v = acc[m][n][r] + ((BMODE == BIAS_N) ? bias[col] : bm);
                if (OUT_BF16) Cb[(size_t)row * ldc + col] = f2bf(v);
                else          Ch[(size_t)row * ldc + col] = (_Float16)v;
            }
        }
    }
}

// ---------------------------------------------------------------------------
// Batched projection GEMM: one dispatch for q, k, v (192 blocks of 512 thr).
// ---------------------------------------------------------------------------
__global__ __launch_bounds__(512, 2)
void proj256_kernel(const ushort* __restrict__ XT, const ushort* __restrict__ ZT,
                    const ushort* __restrict__ Wqb, const ushort* __restrict__ Wkb,
                    const ushort* __restrict__ Wvb,
                    const float* __restrict__ bq, const float* __restrict__ bk,
                    const float* __restrict__ bv,
                    ushort* __restrict__ qT, ushort* __restrict__ kT,
                    ushort* __restrict__ vB)
{
    extern __shared__ char smem[];
    int b = blockIdx.x;
    if (b < 64) {
        gemm256<BIAS_N, true, false>(XT, Wqb, bq, qT, LXc, DAc, DXc, DXc, DXc, DAc,
                                     (b >> 2) * 256, (b & 3) * 256, 0, 0, smem);
    } else if (b < 128) {
        b -= 64;
        gemm256<BIAS_N, true, false>(ZT, Wkb, bk, kT, LZc, DAc, DZc, DZc, DZc, DAc,
                                     (b >> 2) * 256, (b & 3) * 256, 0, 0, smem);
    } else {
        b -= 128;
        gemm256<BIAS_M, true, false>(Wvb, ZT, bv, vB, DOc, LZc, DZc, DZc, DZc, LZc,
                                     (b >> 4) * 256, (b & 15) * 256, 0, 0, smem);
    }
}

// Score GEMM: sTb[x,z] = sum_d qT[x,d] kT[z,d]  (bf16 out, no mask). 256 blocks.
__global__ __launch_bounds__(512, 2)
void score256_kernel(const ushort* __restrict__ qT, const ushort* __restrict__ kT,
                     ushort* __restrict__ sTb)
{
    extern __shared__ char smem[];
    const int b = blockIdx.x;
    gemm256<BIAS_NONE, true, false>(qT, kT, nullptr, sTb, LXc, LZc, DAc, DAc, DAc, LZc,
                                    (b >> 4) * 256, (b & 15) * 256, 0, 0, smem);
}

// Out GEMM split-K=4: P[z][o][x] fp16 partials. grid (16,4,4) = 256 blocks.
__global__ __launch_bounds__(512, 2)
void out256_kernel(const ushort* __restrict__ vB, const ushort* __restrict__ sTb,
                   _Float16* __restrict__ P)
{
    extern __shared__ char smem[];
    gemm256<BIAS_NONE, false, true>(vB, sTb, nullptr, P, DOc, LXc, LZc / 4,
                                    LZc, LZc, LXc,
                                    blockIdx.y * 256, blockIdx.x * 256,
                                    blockIdx.z * (LZc / 4), blockIdx.z, smem);
}

// ---------------------------------------------------------------------------
// Prep (one dispatch, 13312 blocks) — round-1 measured-best, FROZEN:
// X->XT bf16 LDS transpose, Z->ZT, Wq/Wk/Wv fp32->bf16, mask pack
// (2048-block spread; r8 proved concentrating it loses).
// ---------------------------------------------------------------------------
__global__ __launch_bounds__(256)
void prep_kernel(const float* __restrict__ X, const float* __restrict__ Z,
                 const float* __restrict__ Wq, const float* __restrict__ Wk,
                 const float* __restrict__ Wv, const int* __restrict__ mask,
                 ushort* __restrict__ XT, ushort* __restrict__ ZT,
                 ushort* __restrict__ Wqb, ushort* __restrict__ Wkb,
                 ushort* __restrict__ Wvb, unsigned* __restrict__ bits)
{
    __shared__ float tile[32][33];
    const int tid = threadIdx.x;
    int b = blockIdx.x;

    if (b < 8192) {   // two transposes, 4096 blocks each: (R=1024, C=4096)
        const float* in  = (b < 4096) ? X : Z;
        ushort*      out = (b < 4096) ? XT : ZT;
        const int local = b & 4095;
        const int bx = local & 127, by = local >> 7;     // C/32=128 tiles in x
        const int c0 = bx * 32, r0 = by * 32;
        const int tx = tid & 31, ty = tid >> 5;          // 32 x 8
        #pragma unroll
        for (int i = 0; i < 32; i += 8)
            tile[ty + i][tx] = in[(size_t)(r0 + ty + i) * LXc + c0 + tx];
        __syncthreads();
        #pragma unroll
        for (int i = 0; i < 32; i += 8)
            out[(size_t)(c0 + ty + i) * DXc + r0 + tx] = f2bf(tile[tx][ty + i]);
        return;
    }
    if (b < 11264) {  // three weight converts, 1024 blocks each (1M elems)
        b -= 8192;
        const float* in  = (b < 1024) ? Wq : (b < 2048) ? Wk : Wv;
        ushort*      out = (b < 1024) ? Wqb : (b < 2048) ? Wkb : Wvb;
        const int local = b & 1023;
        const size_t i = ((size_t)local * 256 + tid) * 4;
        float4 f = *reinterpret_cast<const float4*>(in + i);
        ushort4 u;
        u.x = f2bf(f.x); u.y = f2bf(f.y); u.z = f2bf(f.z); u.w = f2bf(f.w);
        *reinterpret_cast<ushort4*>(out + i) = u;
        return;
    }
    // mask pack: 2048 blocks; block = (xb in [0,16), zb in [0,128))
    b -= 11264;
    const int xb = b & 15, zb = b >> 4;
    const int x  = xb * 256 + tid;
    const int z0 = zb * 32;
    unsigned w = 0;
    #pragma unroll 8
    for (int i = 0; i < 32; ++i)
        w |= (mask[(size_t)(z0 + i) * LXc + x] != 0 ? 1u : 0u) << i;
    bits[(size_t)x * (LZc / 32) + zb] = w;
}

// ---------------------------------------------------------------------------
// Row softmax over bf16 sTb (LX x LZ) with packed mask bits; scale 1/32,
// masked -> -1000/32; softmax over the row; bf16 in place.  (r1 version)
// ---------------------------------------------------------------------------
__global__ __launch_bounds__(256)
void softmax_kernel(ushort* __restrict__ sTb, const unsigned* __restrict__ bits)
{
    const int x   = blockIdx.x;
    const int tid = threadIdx.x;
    ushort* row = sTb + (size_t)x * LZc;
    constexpr float scale = 1.0f / 32.0f;   // 1/sqrt(1024)
    constexpr float MASKV = -1000.0f / 32.0f;

    float v[16];
    float mx = -1e30f;
    #pragma unroll
    for (int r = 0; r < 2; ++r) {
        const uint4 pk = *reinterpret_cast<const uint4*>(row + (size_t)(r * 256 + tid) * 8);
        const unsigned* w = reinterpret_cast<const unsigned*>(&pk);
        const unsigned mb = (bits[(size_t)x * 128 + r * 64 + (tid >> 2)] >> ((tid & 3) * 8)) & 0xffu;
        #pragma unroll
        for (int j = 0; j < 4; ++j) {
            const float lo = ((mb >> (2 * j))     & 1u) ? bflo(w[j]) * scale : MASKV;
            const float hi = ((mb >> (2 * j + 1)) & 1u) ? bfhi(w[j]) * scale : MASKV;
            v[r * 8 + 2 * j]     = lo;
            v[r * 8 + 2 * j + 1] = hi;
            mx = fmaxf(mx, fmaxf(lo, hi));
        }
    }
    __shared__ float redmax[4];
    #pragma unroll
    for (int off = 32; off > 0; off >>= 1)
        mx = fmaxf(mx, __shfl_down(mx, off, 64));
    if ((tid & 63) == 0) redmax[tid >> 6] = mx;
    __syncthreads();
    mx = fmaxf(fmaxf(redmax[0], redmax[1]), fmaxf(redmax[2], redmax[3]));

    float sum = 0.0f;
    #pragma unroll
    for (int i = 0; i < 16; ++i) {
        v[i] = __expf(v[i] - mx);
        sum += v[i];
    }
    __shared__ float redsum[4];
    #pragma unroll
    for (int off = 32; off > 0; off >>= 1)
        sum += __shfl_down(sum, off, 64);
    if ((tid & 63) == 0) redsum[tid >> 6] = sum;
    __syncthreads();
    sum = redsum[0] + redsum[1] + redsum[2] + redsum[3];
    const float inv = 1.0f / sum;

    #pragma unroll
    for (int r = 0; r < 2; ++r) {
        uint4 pk;
        unsigned* w = reinterpret_cast<unsigned*>(&pk);
        #pragma unroll
        for (int j = 0; j < 4; ++j) {
            const unsigned lo = f2bf(v[r * 8 + 2 * j] * inv);
            const unsigned hi = f2bf(v[r * 8 + 2 * j + 1] * inv);
            w[j] = lo | (hi << 16);
        }
        *reinterpret_cast<uint4*>(row + (size_t)(r * 256 + tid) * 8) = pk;
    }
}

// Sum 4 fp16 partial planes -> fp32 out. 8 elems/thread, 2048 blocks.
__global__ __launch_bounds__(256)
void reduce_kernel(const _Float16* __restrict__ P, float* __restrict__ out)
{
    constexpr size_t total = (size_t)DOc * LXc;
    const size_t i = ((size_t)blockIdx.x * 256 + threadIdx.x) * 8;
    float s[8] = {};
    #pragma unroll
    for (int p = 0; p < 4; ++p) {
        const f16x8 t = *reinterpret_cast<const f16x8*>(P + (size_t)p * total + i);
        #pragma unroll
        for (int j = 0; j < 8; ++j) s[j] += (float)t[j];
    }
    float4 o0 = {s[0], s[1], s[2], s[3]};
    float4 o1 = {s[4], s[5], s[6], s[7]};
    *reinterpret_cast<float4*>(out + i)     = o0;
    *reinterpret_cast<float4*>(out + i + 4) = o1;
}

// ---------------------------------------------------------------------------
extern "C" void kernel_launch(void* const* d_in, const int* in_sizes, int n_in,
                              void* d_out, int out_size, void* d_ws, size_t ws_size,
                              hipStream_t stream)
{
    const float* X    = (const float*)d_in[0];
    const float* Z    = (const float*)d_in[1];
    const int*   mask = (const int*)  d_in[2];
    const float* Wq   = (const float*)d_in[3];
    const float* bq   = (const float*)d_in[4];
    const float* Wk   = (const float*)d_in[5];
    const float* bk   = (const float*)d_in[6];
    const float* Wv   = (const float*)d_in[7];
    const float* bv   = (const float*)d_in[8];
    float* out = (float*)d_out;

    // 128 KiB dynamic LDS opt-in (once; host-side, not a stream op).
    static bool inited = false;
    if (!inited) {
        (void)hipFuncSetAttribute((const void*)proj256_kernel,
                                  hipFuncAttributeMaxDynamicSharedMemorySize, 131072);
        (void)hipFuncSetAttribute((const void*)score256_kernel,
                                  hipFuncAttributeMaxDynamicSharedMemorySize, 131072);
        (void)hipFuncSetAttribute((const void*)out256_kernel,
                                  hipFuncAttributeMaxDynamicSharedMemorySize, 131072);
        inited = true;
    }

    // ws layout (106 MB). P (32 MB fp16 at offset 0) OVERLAYS XT/ZT/W/qT and
    // part of kT — all dead by the time the out GEMM writes P.
    char* ws = (char*)d_ws;
    ushort*   XT   = (ushort*)(ws);                   // 8 MB   [dead after proj]
    ushort*   ZT   = (ushort*)(ws + ( 8ull << 20));   // 8 MB   [dead after proj]
    ushort*   Wqb  = (ushort*)(ws + (16ull << 20));   // 2 MB   [dead after proj]
    ushort*   Wkb  = (ushort*)(ws + (18ull << 20));   // 2 MB   [dead after proj]
    ushort*   Wvb  = (ushort*)(ws + (20ull << 20));   // 2 MB   [dead after proj]
    ushort*   qT   = (ushort*)(ws + (22ull << 20));   // 8 MB   [dead after score]
    ushort*   kT   = (ushort*)(ws + (30ull << 20));   // 8 MB   [dead after score]
    _Float16* P    = (_Float16*)(ws);                 // 32 MB  [out partials]
    ushort*   vB   = (ushort*)(ws + (64ull << 20));   // 8 MB
    ushort*   sTb  = (ushort*)(ws + (72ull << 20));   // 32 MB
    unsigned* bits = (unsigned*)(ws + (104ull << 20));// 2 MB

    prep_kernel<<<dim3(13312), 256, 0, stream>>>(X, Z, Wq, Wk, Wv, mask,
                                                 XT, ZT, Wqb, Wkb, Wvb, bits);
    proj256_kernel<<<dim3(192), 512, 131072, stream>>>(XT, ZT, Wqb, Wkb, Wvb,
                                                       bq, bk, bv, qT, kT, vB);
    score256_kernel<<<dim3(256), 512, 131072, stream>>>(qT, kT, sTb);
    softmax_kernel<<<dim3(LXc), 256, 0, stream>>>(sTb, bits);
    out256_kernel<<<dim3(16, 4, 4), 512, 131072, stream>>>(vB, sTb, P);
    reduce_kernel<<<dim3(DOc * LXc / 2048), 256, 0, stream>>>(P, out);
}